// Round 5
// baseline (230.478 us; speedup 1.0000x reference)
//
#include <hip/hip_runtime.h>

#define EPSB 1e-5f

typedef __attribute__((ext_vector_type(8))) short bf16x8;
typedef __attribute__((ext_vector_type(4))) float f32x4;

__device__ __forceinline__ unsigned short f2b(float f) {
  union { float f; unsigned u; } cv; cv.f = f;
  unsigned r = cv.u + 0x7FFFu + ((cv.u >> 16) & 1u);
  return (unsigned short)(r >> 16);
}

// ---------------- K_prep: weight conversions/transposes + BN scale/bias + zero-fill ----
__global__ __launch_bounds__(256) void k_prep(
    const float* __restrict__ pw, const float* __restrict__ cw,
    const float* __restrict__ k1w, const float* __restrict__ k2w,
    const float* __restrict__ g1, const float* __restrict__ b1,
    const float* __restrict__ m1, const float* __restrict__ v1,
    const float* __restrict__ gk, const float* __restrict__ bk,
    const float* __restrict__ mk, const float* __restrict__ vk,
    const float* __restrict__ g2, const float* __restrict__ b2,
    const float* __restrict__ m2, const float* __restrict__ v2,
    unsigned short* __restrict__ pwb, unsigned short* __restrict__ wcb_t,
    unsigned short* __restrict__ wt1, unsigned short* __restrict__ wt2,
    float* __restrict__ sb1, float* __restrict__ sbk, float* __restrict__ sb2,
    float* __restrict__ wsz) {
  int i = blockIdx.x * 256 + threadIdx.x;
  if (i < 333056) wsz[i] = 0.f;           // zero comp_t + k1_t (incl. padded borders)
  if (i < 65536) pwb[i] = f2b(pw[i]);
  int j = i - 65536;
  if (j >= 0 && j < 16384) { int ci = j >> 6, co = j & 63; wcb_t[j] = f2b(cw[co * 256 + ci]); }
  int a = i - 81920;
  if (a >= 0 && a < 36864) {
    int co = a / 576, k = a % 576, tap = k >> 6, ci = k & 63;
    wt1[a] = f2b(k1w[co * 576 + ci * 9 + tap]);
  }
  int c2 = i - 118784;
  if (c2 >= 0 && c2 < 73728) {
    int co = c2 / 576, k = c2 % 576, tap = k >> 6, ci = k & 63;
    wt2[c2] = (co < 100) ? f2b(k2w[co * 576 + ci * 9 + tap]) : (unsigned short)0;
  }
  int s = i - 192512;
  if (s >= 0 && s < 64) { float iv = g1[s] / sqrtf(v1[s] + EPSB); sb1[s] = iv; sb1[64 + s] = b1[s] - m1[s] * iv; }
  if (s >= 64 && s < 128) { int c = s - 64; float iv = gk[c] / sqrtf(vk[c] + EPSB); sbk[c] = iv; sbk[64 + c] = bk[c] - mk[c] * iv; }
  if (s >= 128 && s < 384) { int c = s - 128; float iv = g2[c] / sqrtf(v2[c] + EPSB); sb2[c] = iv; sb2[256 + c] = b2[c] - m2[c] * iv; }
}

// ---------------- K1: 1x1 compress + BN + ReLU -> comp_t[n][52][52][64] bf16 -------
__global__ __launch_bounds__(256) void k_compress(
    const float* __restrict__ x, const unsigned short* __restrict__ wcb_t,
    const float* __restrict__ sb1, unsigned short* __restrict__ comp_t) {
  __shared__ unsigned short wl[16384];   // [ci][co] bf16
  int t = threadIdx.x;
  for (int f = t; f < 2048; f += 256)
    *(bf16x8*)&wl[f * 8] = *(const bf16x8*)&wcb_t[f * 8];
  __syncthreads();
  int idx = blockIdx.x * 256 + t;        // 73728
  int co2 = (idx & 31) * 2;
  int pg = idx >> 5;                     // 0..2303
  int n = pg / 1152;
  int pix0 = (pg % 1152) * 2;
  const float* xp = x + (size_t)n * 256 * 2304 + pix0;
  float a00 = 0.f, a01 = 0.f, a10 = 0.f, a11 = 0.f;
  for (int ci = 0; ci < 256; ++ci) {
    float2 xv = *(const float2*)(xp + (size_t)ci * 2304);
    unsigned pr = *(const unsigned*)&wl[ci * 64 + co2];
    union { unsigned u; float f; } wa, wb;
    wa.u = pr << 16; wb.u = pr & 0xffff0000u;
    a00 = fmaf(xv.x, wa.f, a00); a01 = fmaf(xv.y, wa.f, a01);
    a10 = fmaf(xv.x, wb.f, a10); a11 = fmaf(xv.y, wb.f, a11);
  }
  float s0 = sb1[co2], s1 = sb1[co2 + 1];
  float c0b = sb1[64 + co2], c1b = sb1[64 + co2 + 1];
  float o00 = fmaxf(fmaf(a00, s0, c0b), 0.f), o01 = fmaxf(fmaf(a01, s0, c0b), 0.f);
  float o10 = fmaxf(fmaf(a10, s1, c1b), 0.f), o11 = fmaxf(fmaf(a11, s1, c1b), 0.f);
  int r = pix0 / 48, c = pix0 % 48;
  unsigned short* ob = comp_t + ((size_t)n * 2704 + (r + 2) * 52 + (c + 2)) * 64 + co2;
  unsigned p0 = (unsigned)f2b(o00) | ((unsigned)f2b(o10) << 16);
  unsigned p1 = (unsigned)f2b(o01) | ((unsigned)f2b(o11) << 16);
  *(unsigned*)&ob[0]  = p0;
  *(unsigned*)&ob[64] = p1;
}

// ---------------- K2: 3x3 dil=2 conv via MFMA (K=576) + BN + ReLU -> k1_t ---------
__global__ __launch_bounds__(256) void k_ke1(
    const unsigned short* __restrict__ comp_t, const unsigned short* __restrict__ wt1,
    const float* __restrict__ sbk, unsigned short* __restrict__ k1_t) {
  __shared__ unsigned short sA[16640];   // 5 rows x 52 cols x 64 ci, XOR by col
  int t = threadIdx.x;
  int bid = blockIdx.x;                  // 96
  int n = bid / 48, y = bid % 48;
  const unsigned short* src = comp_t + ((size_t)n * 52 + y) * 52 * 64;
  for (int f = t; f < 2080; f += 256) {
    int g = f >> 3, ci0 = (f & 7) * 8;
    int cc = g % 52, rr = g / 52;
    bf16x8 vv = *(const bf16x8*)&src[(rr * 52 + cc) * 64 + ci0];
    int ba = (((rr * 52 + cc) * 64 + ci0) * 2) ^ ((cc & 7) << 4);
    *(bf16x8*)((char*)sA + ba) = vv;
  }
  __syncthreads();
  int wid = t >> 6, l = t & 63, l15 = l & 15, lg = l >> 4;
  f32x4 acc[3];
  acc[0] = acc[1] = acc[2] = (f32x4){0.f, 0.f, 0.f, 0.f};
  const unsigned short* arow = wt1 + (size_t)(wid * 16 + l15) * 576;
#pragma unroll
  for (int kbi = 0; kbi < 18; ++kbi) {
    int tap = kbi >> 1;
    int ky = tap / 3, kx = tap % 3;
    int ci0 = (kbi & 1) * 32 + lg * 8;
    bf16x8 afr = *(const bf16x8*)&arow[kbi * 32 + lg * 8];
#pragma unroll
    for (int nt = 0; nt < 3; ++nt) {
      int col = nt * 16 + l15 + 2 * kx;
      int ba = (((2 * ky * 52 + col) * 64 + ci0) * 2) ^ ((col & 7) << 4);
      bf16x8 bfr = *(const bf16x8*)((char*)sA + ba);
      acc[nt] = __builtin_amdgcn_mfma_f32_16x16x32_bf16(afr, bfr, acc[nt], 0, 0, 0);
    }
  }
  unsigned short* dst = k1_t + ((size_t)n * 50 + (y + 1)) * 50 * 64;
  int co0 = wid * 16 + lg * 4;
  float s0 = sbk[co0], s1 = sbk[co0 + 1], s2 = sbk[co0 + 2], s3 = sbk[co0 + 3];
  float d0 = sbk[64 + co0], d1 = sbk[64 + co0 + 1], d2 = sbk[64 + co0 + 2], d3 = sbk[64 + co0 + 3];
#pragma unroll
  for (int nt = 0; nt < 3; ++nt) {
    int px = nt * 16 + l15;
    ushort4 pk;
    pk.x = f2b(fmaxf(fmaf(acc[nt][0], s0, d0), 0.f));
    pk.y = f2b(fmaxf(fmaf(acc[nt][1], s1, d1), 0.f));
    pk.z = f2b(fmaxf(fmaf(acc[nt][2], s2, d2), 0.f));
    pk.w = f2b(fmaxf(fmaf(acc[nt][3], s3, d3), 0.f));
    *(ushort4*)&dst[(px + 1) * 64 + co0] = pk;
  }
}

// ---------------- K3: 3x3 conv via MFMA (K=576) -> kern_t[n][pix][112] fp32 -------
__global__ __launch_bounds__(256) void k_ke2(
    const unsigned short* __restrict__ k1_t, const unsigned short* __restrict__ wt2,
    float* __restrict__ kern_t) {
  __shared__ unsigned short sA[9600];    // 3 rows x 50 cols x 64 ci
  int t = threadIdx.x;
  int bid = blockIdx.x;                  // 96
  int n = bid / 48, y = bid % 48;
  const unsigned short* src = k1_t + ((size_t)n * 50 + y) * 50 * 64;
  for (int f = t; f < 1200; f += 256) {
    int g = f >> 3, ci0 = (f & 7) * 8;
    int cc = g % 50, rr = g / 50;
    bf16x8 vv = *(const bf16x8*)&src[(rr * 50 + cc) * 64 + ci0];
    int ba = (((rr * 50 + cc) * 64 + ci0) * 2) ^ ((cc & 7) << 4);
    *(bf16x8*)((char*)sA + ba) = vv;
  }
  __syncthreads();
  int wid = t >> 6, l = t & 63, l15 = l & 15, lg = l >> 4;
  f32x4 acc[2][3];
#pragma unroll
  for (int mi = 0; mi < 2; ++mi)
#pragma unroll
    for (int nt = 0; nt < 3; ++nt) acc[mi][nt] = (f32x4){0.f, 0.f, 0.f, 0.f};
#pragma unroll
  for (int kbi = 0; kbi < 18; ++kbi) {
    int tap = kbi >> 1;
    int ky = tap / 3, kx = tap % 3;
    int ci0 = (kbi & 1) * 32 + lg * 8;
    bf16x8 afr[2];
#pragma unroll
    for (int mi = 0; mi < 2; ++mi)
      afr[mi] = *(const bf16x8*)&wt2[(size_t)((wid * 2 + mi) * 16 + l15) * 576 + kbi * 32 + lg * 8];
#pragma unroll
    for (int nt = 0; nt < 3; ++nt) {
      int col = nt * 16 + l15 + kx;
      int ba = (((ky * 50 + col) * 64 + ci0) * 2) ^ ((col & 7) << 4);
      bf16x8 bfr = *(const bf16x8*)((char*)sA + ba);
      acc[0][nt] = __builtin_amdgcn_mfma_f32_16x16x32_bf16(afr[0], bfr, acc[0][nt], 0, 0, 0);
      acc[1][nt] = __builtin_amdgcn_mfma_f32_16x16x32_bf16(afr[1], bfr, acc[1][nt], 0, 0, 0);
    }
  }
#pragma unroll
  for (int mi = 0; mi < 2; ++mi) {
    int co0 = (wid * 2 + mi) * 16 + lg * 4;
    if (co0 < 100) {
#pragma unroll
      for (int nt = 0; nt < 3; ++nt) {
        int px = nt * 16 + l15;
        float4 vv = {acc[mi][nt][0], acc[mi][nt][1], acc[mi][nt][2], acc[mi][nt][3]};
        *(float4*)&kern_t[((size_t)n * 2304 + y * 48 + px) * 112 + co0] = vv;
      }
    }
  }
}

// ---------------- K4: LDS-staged softmax + bilinear + fold 25->9 (stride-12 out) ----
__global__ __launch_bounds__(256) void k_w9sm(const float* __restrict__ kern_t,
                                              float* __restrict__ w9) {
  __shared__ float ks[3 * 48 * 116];     // [slot][sx][116 pad]
  int bid = blockIdx.x;                  // 96
  int n = bid / 48, k = bid % 48;
  int t = threadIdx.x;
  int rows[3] = {max(k - 1, 0), k, min(k + 1, 47)};
#pragma unroll
  for (int s = 0; s < 3; ++s) {
    const float* src = kern_t + ((size_t)n * 2304 + rows[s] * 48) * 112;
    for (int f = t; f < 1344; f += 256) {
      float4 vv = *(const float4*)&src[f * 4];
      int sx = f / 28, c = (f % 28) * 4;
      *(float4*)&ks[(s * 48 + sx) * 116 + c] = vv;
    }
  }
  __syncthreads();
#pragma unroll
  for (int it = 0; it < 3; ++it) {
    int f = t + it * 256;                // 0..767
    int half = f / 384, rem = f % 384;
    int w2 = rem >> 2, u = rem & 3;
    int y96 = 2 * k + half;
    float syf = fminf(fmaxf(y96 * 0.5f - 0.25f, 0.f), 47.f);
    int y0 = (int)syf; int y1 = min(y0 + 1, 47); float wy = syf - (float)y0;
    int sl0 = (y0 == k) ? 1 : 0;
    int sl1 = (y1 == k) ? 1 : 2;
    float sxf = fminf(fmaxf(w2 * 0.5f - 0.25f, 0.f), 47.f);
    int x0 = (int)sxf; int x1 = min(x0 + 1, 47); float wx = sxf - (float)x0;
    float bl[25];
#pragma unroll
    for (int kk = 0; kk < 25; ++kk) bl[kk] = 0.f;
    float ws4[4] = {(1.f - wx) * (1.f - wy), wx * (1.f - wy), (1.f - wx) * wy, wx * wy};
    int ssy[4] = {sl0, sl0, sl1, sl1};
    int ssx[4] = {x0, x1, x0, x1};
#pragma unroll
    for (int s = 0; s < 4; ++s) {
      const float* p = &ks[(ssy[s] * 48 + ssx[s]) * 116 + u * 25];
      float vv[25], mx = -3.4e38f;
#pragma unroll
      for (int kk = 0; kk < 25; ++kk) { vv[kk] = p[kk]; mx = fmaxf(mx, vv[kk]); }
      float sum = 0.f;
#pragma unroll
      for (int kk = 0; kk < 25; ++kk) { vv[kk] = __expf(vv[kk] - mx); sum += vv[kk]; }
      float rs = ws4[s] / sum;
#pragma unroll
      for (int kk = 0; kk < 25; ++kk) bl[kk] = fmaf(vv[kk], rs, bl[kk]);
    }
#pragma unroll
    for (int kh = 0; kh < 5; ++kh) {
      bool vy = (unsigned)(y96 + kh - 2) < 96u;
#pragma unroll
      for (int kw = 0; kw < 5; ++kw) {
        bool vx = (unsigned)(w2 + kw - 2) < 96u;
        if (!(vy && vx)) bl[kh * 5 + kw] = 0.f;
      }
    }
    int py = y96 & 1, px_ = w2 & 1;
    float cc0[5], cc1[5], cc2[5];
#pragma unroll
    for (int kh = 0; kh < 5; ++kh) {
      cc0[kh] = px_ ? bl[kh * 5 + 0] : bl[kh * 5 + 0] + bl[kh * 5 + 1];
      cc1[kh] = px_ ? bl[kh * 5 + 1] + bl[kh * 5 + 2] : bl[kh * 5 + 2] + bl[kh * 5 + 3];
      cc2[kh] = px_ ? bl[kh * 5 + 3] + bl[kh * 5 + 4] : bl[kh * 5 + 4];
    }
    float* op = w9 + (((size_t)(n * 96 + y96) * 96 + w2) * 4 + u) * 12;
    op[0] = py ? cc0[0] : cc0[0] + cc0[1];
    op[1] = py ? cc1[0] : cc1[0] + cc1[1];
    op[2] = py ? cc2[0] : cc2[0] + cc2[1];
    op[3] = py ? cc0[1] + cc0[2] : cc0[2] + cc0[3];
    op[4] = py ? cc1[1] + cc1[2] : cc1[2] + cc1[3];
    op[5] = py ? cc2[1] + cc2[2] : cc2[2] + cc2[3];
    op[6] = py ? cc0[3] + cc0[4] : cc0[4];
    op[7] = py ? cc1[3] + cc1[4] : cc1[4];
    op[8] = py ? cc2[3] + cc2[4] : cc2[4];
  }
}

// ---------------- K6 v5: pipelined reassembly (VALU) || MFMA proj, dbuf finT -------
// vals for chunk c: 9-tap reassembly into regs; chunk = one Y row (32 px).
__device__ __forceinline__ void compute_vals(
    const float* __restrict__ xls, const float* __restrict__ w9s,
    int c, int ch, int u, int jb, float* __restrict__ v0, float* __restrict__ v1) {
  int p = c & 1;
  const float* xc0 = &xls[((2 * p + 0) * 64 + ch) * 35];
  const float* xc1 = &xls[((2 * p + 1) * 64 + ch) * 35];
  int cbase = jb >> 1;
  float w60[3][6], w61[3][6];
#pragma unroll
  for (int ry = 0; ry < 3; ++ry)
#pragma unroll
    for (int cc = 0; cc < 6; ++cc) {
      w60[ry][cc] = xc0[ry * 11 + cbase + cc];
      w61[ry][cc] = xc1[ry * 11 + cbase + cc];
    }
  const float* wrow = &w9s[((c >> 1) * 16 + jb) * 48 + u * 12];
#pragma unroll
  for (int jj = 0; jj < 8; ++jj) {
    const float* wt = wrow + jj * 48;
    float4 wa = *(const float4*)wt;
    float4 wb = *(const float4*)(wt + 4);
    float w8 = wt[8];
    int cs = jj >> 1;
    float a0 = w60[0][cs] * wa.x;
    a0 = fmaf(w60[0][cs + 1], wa.y, a0);
    a0 = fmaf(w60[0][cs + 2], wa.z, a0);
    a0 = fmaf(w60[1][cs],     wa.w, a0);
    a0 = fmaf(w60[1][cs + 1], wb.x, a0);
    a0 = fmaf(w60[1][cs + 2], wb.y, a0);
    a0 = fmaf(w60[2][cs],     wb.z, a0);
    a0 = fmaf(w60[2][cs + 1], wb.w, a0);
    a0 = fmaf(w60[2][cs + 2], w8,   a0);
    float a1 = w61[0][cs] * wa.x;
    a1 = fmaf(w61[0][cs + 1], wa.y, a1);
    a1 = fmaf(w61[0][cs + 2], wa.z, a1);
    a1 = fmaf(w61[1][cs],     wa.w, a1);
    a1 = fmaf(w61[1][cs + 1], wb.x, a1);
    a1 = fmaf(w61[1][cs + 2], wb.y, a1);
    a1 = fmaf(w61[2][cs],     wb.z, a1);
    a1 = fmaf(w61[2][cs + 1], wb.w, a1);
    a1 = fmaf(w61[2][cs + 2], w8,   a1);
    v0[jj] = a0;
    v1[jj] = a1;
  }
}

__global__ __launch_bounds__(512, 4) void k_reassemble_proj(
    const float* __restrict__ x, const float* __restrict__ w9,
    const unsigned short* __restrict__ pwb, const float* __restrict__ sb2,
    float* __restrict__ out) {
  __shared__ float xls[256 * 35];           // [parity(4)*64 + ch][3*11 pad 35]
  __shared__ float w9s[1536];               // [half(2)][16 w][4 u][12]
  __shared__ float sb2s[512];
  __shared__ unsigned short finT[2][32 * 256]; // dbuf: 32 px x 256 ci, swizzled

  int blk = blockIdx.x;                     // 576 = 2 * 48 * 6
  int n = blk / 288;
  int r = blk % 288;
  int y48 = r / 6;
  int xt = r % 6;
  int X0 = xt * 32;
  int x480 = xt * 8;
  int t = threadIdx.x;

  sb2s[t] = sb2[t];
  {
    const float* wbase = w9 + ((size_t)(n * 96 + 2 * y48) * 96 + xt * 16) * 48;
    for (int f = t; f < 1536; f += 512) {
      int half = f / 768, o = f - half * 768;
      w9s[f] = wbase[(size_t)half * 4608 + o];
    }
  }
  const float* xb = x + (size_t)n * 256 * 2304;
  for (int f = t; f < 8448; f += 512) {
    int c = f / 33, rc = f - c * 33;
    int ry = rc / 11, cx = rc - ry * 11;
    int sy = min(max(y48 + ry - 1, 0), 47);
    int sx = min(max(x480 + cx - 1, 0), 47);
    int slot = (c & 3) * 64 + (c >> 2);
    xls[slot * 35 + rc] = xb[(size_t)c * 2304 + sy * 48 + sx];
  }
  __syncthreads();

  int ci = t & 255, half = t >> 8;
  int u = ci >> 6, ch = ci & 63;
  int cb = ci >> 3, crr = ci & 7;
  int jb = half * 8;
  int wid = t >> 6, l = t & 63, l15 = l & 15, lg = l >> 4;
  const unsigned short* a0p = pwb + (size_t)(wid * 2 * 16 + l15) * 256;
  const unsigned short* a1p = a0p + 16 * 256;
  size_t outn = (size_t)n * 256 * 36864;
  int Ybase = 4 * y48;

  float v0[8], v1[8];
  // prologue: vals(0) -> finT[0]
  compute_vals(xls, w9s, 0, ch, u, jb, v0, v1);
#pragma unroll
  for (int jj = 0; jj < 8; ++jj) {
    int px0 = 2 * (jb + jj), px1 = px0 + 1;
    finT[0][px0 * 256 + ((cb ^ (px0 & 7)) * 8 + crr)] = f2b(v0[jj]);
    finT[0][px1 * 256 + ((cb ^ (px1 & 7)) * 8 + crr)] = f2b(v1[jj]);
  }
  __syncthreads();

#pragma unroll
  for (int c = 0; c < 4; ++c) {
    // phase 2: MFMA C[256 o][32 px] = pwb @ finT[c&1]
    f32x4 acc[2][2];
#pragma unroll
    for (int mi = 0; mi < 2; ++mi)
#pragma unroll
      for (int nt = 0; nt < 2; ++nt) acc[mi][nt] = (f32x4){0.f, 0.f, 0.f, 0.f};
#pragma unroll
    for (int kbi = 0; kbi < 8; ++kbi) {
      bf16x8 afr0 = *(const bf16x8*)&a0p[kbi * 32 + lg * 8];
      bf16x8 afr1 = *(const bf16x8*)&a1p[kbi * 32 + lg * 8];
      int cbk = kbi * 4 + lg;
#pragma unroll
      for (int nt = 0; nt < 2; ++nt) {
        int row = nt * 16 + l15;
        bf16x8 bfr = *(const bf16x8*)&finT[c & 1][row * 256 + ((cbk ^ (row & 7)) * 8)];
        acc[0][nt] = __builtin_amdgcn_mfma_f32_16x16x32_bf16(afr0, bfr, acc[0][nt], 0, 0, 0);
        acc[1][nt] = __builtin_amdgcn_mfma_f32_16x16x32_bf16(afr1, bfr, acc[1][nt], 0, 0, 0);
      }
    }
    // overlap: compute next chunk's reassembly in registers (VALU pipe)
    if (c < 3) compute_vals(xls, w9s, c + 1, ch, u, jb, v0, v1);
    // stores for this chunk
    {
      float* orow = out + outn + (size_t)(Ybase + c) * 192 + X0;
#pragma unroll
      for (int mi = 0; mi < 2; ++mi) {
#pragma unroll
        for (int r4 = 0; r4 < 4; ++r4) {
          int o = (wid * 2 + mi) * 16 + lg * 4 + r4;
          float sc = sb2s[o], bi = sb2s[256 + o];
#pragma unroll
          for (int nt = 0; nt < 2; ++nt) {
            float val = fmaxf(fmaf(acc[mi][nt][r4], sc, bi), 0.f);
            orow[(size_t)o * 36864 + nt * 16 + l15] = val;
          }
        }
      }
    }
    if (c < 3) {
#pragma unroll
      for (int jj = 0; jj < 8; ++jj) {
        int px0 = 2 * (jb + jj), px1 = px0 + 1;
        finT[(c + 1) & 1][px0 * 256 + ((cb ^ (px0 & 7)) * 8 + crr)] = f2b(v0[jj]);
        finT[(c + 1) & 1][px1 * 256 + ((cb ^ (px1 & 7)) * 8 + crr)] = f2b(v1[jj]);
      }
      __syncthreads();
    }
  }
}

extern "C" void kernel_launch(void* const* d_in, const int* in_sizes, int n_in,
                              void* d_out, int out_size, void* d_ws, size_t ws_size,
                              hipStream_t stream) {
  const float* x   = (const float*)d_in[0];
  const float* cw  = (const float*)d_in[1];
  const float* g1  = (const float*)d_in[2];
  const float* b1  = (const float*)d_in[3];
  const float* m1  = (const float*)d_in[4];
  const float* v1  = (const float*)d_in[5];
  const float* k1w = (const float*)d_in[6];
  const float* gk  = (const float*)d_in[7];
  const float* bk  = (const float*)d_in[8];
  const float* mk  = (const float*)d_in[9];
  const float* vk  = (const float*)d_in[10];
  const float* k2w = (const float*)d_in[11];
  const float* pw  = (const float*)d_in[12];
  const float* g2  = (const float*)d_in[13];
  const float* b2  = (const float*)d_in[14];
  const float* m2  = (const float*)d_in[15];
  const float* v2  = (const float*)d_in[16];
  float* out = (float*)d_out;
  float* ws  = (float*)d_ws;

  unsigned short* comp_t = (unsigned short*)ws;            // 346112 bf16
  unsigned short* k1_t   = (unsigned short*)(ws + 173056); // 320000 bf16
  float* kern_t = ws + 333056;                             // 516096 f32
  float* w9     = ws + 849152;                             // 884736 f32 (stride 12)
  unsigned short* pwb   = (unsigned short*)(ws + 1733888); // 65536 bf16
  unsigned short* wcb_t = (unsigned short*)(ws + 1766656); // 16384 bf16
  unsigned short* wt1   = (unsigned short*)(ws + 1774848); // 36864 bf16
  unsigned short* wt2   = (unsigned short*)(ws + 1793280); // 73728 bf16
  float* sb1 = ws + 1830144;                               // 128
  float* sbk = ws + 1830272;                               // 128
  float* sb2 = ws + 1830400;                               // 512

  k_prep<<<1302, 256, 0, stream>>>(pw, cw, k1w, k2w, g1, b1, m1, v1,
                                   gk, bk, mk, vk, g2, b2, m2, v2,
                                   pwb, wcb_t, wt1, wt2, sb1, sbk, sb2, ws);
  k_compress<<<288, 256, 0, stream>>>(x, wcb_t, sb1, comp_t);
  k_ke1<<<96, 256, 0, stream>>>(comp_t, wt1, sbk, k1_t);
  k_ke2<<<96, 256, 0, stream>>>(k1_t, wt2, kern_t);
  k_w9sm<<<96, 256, 0, stream>>>(kern_t, w9);
  k_reassemble_proj<<<576, 512, 0, stream>>>(x, w9, pwb, sb2, out);
}